// Round 6
// baseline (390.778 us; speedup 1.0000x reference)
//
#include <hip/hip_runtime.h>

typedef unsigned short u16;
typedef __attribute__((ext_vector_type(8))) __bf16 bf16x8;
typedef __attribute__((ext_vector_type(4))) float floatx4;

__device__ inline float bf2f(u16 u) {
  union { unsigned u; float f; } v; v.u = ((unsigned)u) << 16; return v.f;
}
__device__ inline u16 f2bf(float f) {
  union { float f; unsigned u; } v; v.f = f;
  unsigned r = v.u + 0x7fffu + ((v.u >> 16) & 1u);
  return (u16)(r >> 16);
}

__device__ inline void glds16(const u16* g, u16* l) {
  __builtin_amdgcn_global_load_lds((const __attribute__((address_space(1))) void*)g,
                                   (__attribute__((address_space(3))) void*)l, 16, 0, 0);
}

// ---------------- dtype probe: fp32-as-u16 halves have wild exponents ----------------
__global__ __launch_bounds__(256) void detect_k(const u16* __restrict__ w, int* flag)
{
  __shared__ int cnt;
  if (threadIdx.x == 0) cnt = 0;
  __syncthreads();
  int c = 0;
  for (int i = threadIdx.x; i < 16384; i += 256) {
    const int e = (w[i] >> 7) & 0xFF;
    if (e < 64 || e > 191) ++c;
  }
  atomicAdd(&cnt, c);
  __syncthreads();
  if (threadIdx.x == 0) *flag = (cnt > 256) ? 1 : 0;   // 1 => inputs are fp32
}

// ---------------- x -> bf16 (copy or downcast), 4 elems/thread ----------------
__global__ __launch_bounds__(256) void cast_x_k(const void* __restrict__ in,
                                                u16* __restrict__ out,
                                                int n4, const int* __restrict__ flag)
{
  const int i = blockIdx.x * 256 + threadIdx.x;
  if (i >= n4) return;
  if (*flag) {
    const float4 v = ((const float4*)in)[i];
    u16 o0 = f2bf(v.x), o1 = f2bf(v.y), o2 = f2bf(v.z), o3 = f2bf(v.w);
    uint2 p; p.x = (unsigned)o0 | ((unsigned)o1 << 16); p.y = (unsigned)o2 | ((unsigned)o3 << 16);
    ((uint2*)out)[i] = p;
  } else {
    ((uint2*)out)[i] = ((const uint2*)in)[i];
  }
}

// ---------------- cast+transpose: in [R,C] (flag? f32 : bf16) -> bf16 [C,R] ----------------
__global__ __launch_bounds__(256) void ct_transpose_k(const void* __restrict__ in,
                                                      u16* __restrict__ out,
                                                      int R, int C, const int* __restrict__ flag)
{
  __shared__ u16 tile[32][33];
  const int f = *flag;
  const int c0 = blockIdx.x * 32, r0 = blockIdx.y * 32;
  const int tx = threadIdx.x & 31, ty = threadIdx.x >> 5;
#pragma unroll
  for (int i = ty; i < 32; i += 8) {
    const size_t idx = (size_t)(r0 + i) * C + (c0 + tx);
    tile[i][tx] = f ? f2bf(((const float*)in)[idx]) : ((const u16*)in)[idx];
  }
  __syncthreads();
#pragma unroll
  for (int i = ty; i < 32; i += 8)
    out[(size_t)(c0 + i) * R + (r0 + tx)] = tile[tx][i];
}

// ---------------- bias -> fp32 ----------------
__global__ __launch_bounds__(256) void bias_cast_k(const void* __restrict__ in,
                                                   float* __restrict__ out,
                                                   int n, const int* __restrict__ flag)
{
  const int i = blockIdx.x * 256 + threadIdx.x;
  if (i >= n) return;
  out[i] = *flag ? ((const float*)in)[i] : bf2f(((const u16*)in)[i]);
}

// ---------------- GEMM C[M,N] = A[M,K] @ Bt[N,K]^T (+bias), bf16 MFMA ----------------
// 224x256 tile, 8 waves (2M x 4N), BK=32, 4-slot LDS ring (120 KiB), 1 block/CU.
// KEY CHANGE (round 6): 2-K-tile barrier-free windows. Five prior variants all
// measured ~2820 cyc/tile = LDS port + MFMA + DMA fully SERIAL, because a barrier
// in/at-end-of every K-tile re-phase-locks all 8 waves: the port serves everyone
// round-robin -> all waves finish reads together, MFMA together, pipes alternate.
// Now: exactly ONE fused vmcnt(0)+s_barrier per 2 tiles. Inside the window, 4
// read-bursts interleave 4 MFMA clusters gated only by in-order lgkm counts:
// c1(e) waits window-top reads (only exposed bubble ~200cyc); c2(e)'s a36P drains
// under c1(e); c1(o)'s bQ/a02Q drain under c2(e); c2(o)'s a36Q drains under c1(o).
// No rendezvous for ~2800 cyc => waves de-phase and the LDS port feeds during
// other waves' MFMA bursts (setprio arbitration now has role diversity).
// Race audit: every ds_read is lgkm-retired by its consuming MFMA cluster BEFORE
// the next barrier; DMA for tiles 2w+2/2w+3 issues AFTER the barrier proving
// tiles 2w-2/2w-1 (same ring slots) were fully read. Visibility: each wave fuses
// its own vmcnt(0) with the barrier.
// Requires M%224==0, N%256==0, K%64==0 (even tile count), K>=128.
__global__ __launch_bounds__(512, 2) void gemm256(
    const u16* __restrict__ A, const u16* __restrict__ Bt,
    const float* __restrict__ bias, void* __restrict__ C,
    int M, int N, int K, const int* __restrict__ flag, int flagOut)
{
  __shared__ u16 smem[61440];   // A ring: 4 x 7168 u16, B ring: 4 x 8192 u16
  u16* As = smem;
  u16* Bs = smem + 28672;
  const int t = threadIdx.x;
  const int wave = t >> 6, lane = t & 63;
  const int quad = lane >> 4, l15 = lane & 15;
  const int wm = wave >> 2, wn = wave & 3;

  // bijective XCD swizzle, then M-major so consecutive blocks in an XCD chunk
  // share the B-panel (L2-resident)
  const int nwg = gridDim.x;
  const int q = nwg >> 3, r8 = nwg & 7;
  const int xcd = blockIdx.x & 7, loc = blockIdx.x >> 3;
  const int wg = (xcd < r8 ? xcd * (q + 1) : r8 * (q + 1) + (xcd - r8) * q) + loc;
  const int MT = M / 224;
  const int mt = wg % MT, ntile = wg / MT;
  const size_t m0 = (size_t)mt * 224;
  const size_t n0 = (size_t)ntile << 8;

  // LDS read offsets (u16 units within one tile slot).
  // Layout: line = row>>1 (128 B), slot h = (row&1)*4 + kgroup, stored h^(line&7).
  int addrA[7], addrB[4];
#pragma unroll
  for (int i = 0; i < 7; ++i) {
    const int row = wm * 112 + i * 16 + l15;
    const int hs = (((row & 1) << 2) | quad) ^ ((row >> 1) & 7);
    addrA[i] = (row >> 1) * 64 + hs * 8;
  }
#pragma unroll
  for (int j = 0; j < 4; ++j) {
    const int row = wn * 64 + j * 16 + l15;
    const int hs = (((row & 1) << 2) | quad) ^ ((row >> 1) & 7);
    addrB[j] = (row >> 1) * 64 + hs * 8;
  }

  // staging: invert the swizzle to find (row, kgroup) fetched into stored slot S.
  // A tile = 896 slots: p0 covers S=t (all), p1 covers S=512+t (t<384 => waves 0-5).
  // B tile = 1024 slots: p0 S=t, p1 S=512+t (all threads).
  const u16 *aSrc0, *aSrc1, *bSrc0, *bSrc1;
  {
    const int S0 = t, S1 = 512 + t;
    int line = S0 >> 3, h = (S0 & 7) ^ (line & 7);
    int row = line * 2 + (h >> 2), g = (h & 3) * 8;
    aSrc0 = A + (m0 + row) * (size_t)K + g;
    bSrc0 = Bt + (n0 + row) * (size_t)K + g;
    line = S1 >> 3; h = (S1 & 7) ^ (line & 7);
    row = line * 2 + (h >> 2); g = (h & 3) * 8;
    aSrc1 = A + (m0 + row) * (size_t)K + g;     // valid only for t<384 (row<224)
    bSrc1 = Bt + (n0 + row) * (size_t)K + g;
  }
  const int dst0 = wave * 512;          // u16 units; HW adds lane*16B
  const int dst1 = 4096 + wave * 512;

  const int NTk = K >> 5;
  const int NW = NTk >> 1;
  floatx4 acc[7][4] = {};

  // prologue: stage K-tiles 0..3 into the full ring
#pragma unroll
  for (int pt = 0; pt < 4; ++pt) {
    glds16(aSrc0 + pt * 32, As + pt * 7168 + dst0);
    if (wave < 6) glds16(aSrc1 + pt * 32, As + pt * 7168 + dst1);
    glds16(bSrc0 + pt * 32, Bs + pt * 8192 + dst0);
    glds16(bSrc1 + pt * 32, Bs + pt * 8192 + dst1);
  }
  // tiles 0,1 landed (2,3 in flight)
  if (wave < 6) asm volatile("s_waitcnt vmcnt(8)" ::: "memory");
  else          asm volatile("s_waitcnt vmcnt(6)" ::: "memory");
  asm volatile("s_barrier" ::: "memory");

  for (int w = 0; w < NW; ++w) {
    // window-top sync (w>0): waits tiles 2w,2w+1 (issued one full window ago),
    // fused per-wave so nothing slips between the wait and the cross-wave sync.
    if (w) asm volatile("s_waitcnt vmcnt(0)\n\ts_barrier" ::: "memory");

    const int e = 2 * w;
    const u16* sAe = As + (e & 3) * 7168;
    const u16* sBe = Bs + (e & 3) * 8192;
    const u16* sAo = As + ((e + 1) & 3) * 7168;
    const u16* sBo = Bs + ((e + 1) & 3) * 8192;

    // DMA for tiles e+2, e+3 (w=0's pair was staged by the prologue). Overwrites
    // slots of tiles e-2, e-1, fully read before the barrier just crossed.
    if (w && e + 2 < NTk) {
      const int e2 = e + 2, o2 = e + 3;
      glds16(aSrc0 + e2 * 32, As + (e2 & 3) * 7168 + dst0);
      if (wave < 6) glds16(aSrc1 + e2 * 32, As + (e2 & 3) * 7168 + dst1);
      glds16(bSrc0 + e2 * 32, Bs + (e2 & 3) * 8192 + dst0);
      glds16(bSrc1 + e2 * 32, Bs + (e2 & 3) * 8192 + dst1);
      glds16(aSrc0 + o2 * 32, As + (o2 & 3) * 7168 + dst0);
      if (wave < 6) glds16(aSrc1 + o2 * 32, As + (o2 & 3) * 7168 + dst1);
      glds16(bSrc0 + o2 * 32, Bs + (o2 & 3) * 8192 + dst0);
      glds16(bSrc1 + o2 * 32, Bs + (o2 & 3) * 8192 + dst1);
    }

    // ---- even tile: reads then c1/c2, pipelined via in-order lgkm ----
    bf16x8 bP[4], a02P[3], a36P[4];
#pragma unroll
    for (int j = 0; j < 4; ++j) bP[j] = *(const bf16x8*)(sBe + addrB[j]);
#pragma unroll
    for (int i = 0; i < 3; ++i) a02P[i] = *(const bf16x8*)(sAe + addrA[i]);
#pragma unroll
    for (int i = 0; i < 4; ++i) a36P[i] = *(const bf16x8*)(sAe + addrA[3 + i]);

    __builtin_amdgcn_s_setprio(1);
#pragma unroll
    for (int i = 0; i < 3; ++i)
#pragma unroll
      for (int j = 0; j < 4; ++j)
        acc[i][j] = __builtin_amdgcn_mfma_f32_16x16x32_bf16(a02P[i], bP[j], acc[i][j], 0, 0, 0);
    __builtin_amdgcn_s_setprio(0);

    bf16x8 bQ[4], a02Q[3];
#pragma unroll
    for (int j = 0; j < 4; ++j) bQ[j] = *(const bf16x8*)(sBo + addrB[j]);
#pragma unroll
    for (int i = 0; i < 3; ++i) a02Q[i] = *(const bf16x8*)(sAo + addrA[i]);

    __builtin_amdgcn_s_setprio(1);
#pragma unroll
    for (int i = 0; i < 4; ++i)
#pragma unroll
      for (int j = 0; j < 4; ++j)
        acc[3 + i][j] = __builtin_amdgcn_mfma_f32_16x16x32_bf16(a36P[i], bP[j], acc[3 + i][j], 0, 0, 0);
    __builtin_amdgcn_s_setprio(0);

    // ---- odd tile ----
    bf16x8 a36Q[4];
#pragma unroll
    for (int i = 0; i < 4; ++i) a36Q[i] = *(const bf16x8*)(sAo + addrA[3 + i]);

    __builtin_amdgcn_s_setprio(1);
#pragma unroll
    for (int i = 0; i < 3; ++i)
#pragma unroll
      for (int j = 0; j < 4; ++j)
        acc[i][j] = __builtin_amdgcn_mfma_f32_16x16x32_bf16(a02Q[i], bQ[j], acc[i][j], 0, 0, 0);
#pragma unroll
    for (int i = 0; i < 4; ++i)
#pragma unroll
      for (int j = 0; j < 4; ++j)
        acc[3 + i][j] = __builtin_amdgcn_mfma_f32_16x16x32_bf16(a36Q[i], bQ[j], acc[3 + i][j], 0, 0, 0);
    __builtin_amdgcn_s_setprio(0);
  }

  // epilogue scratch overlaps ring slots -> full sync first (also drains all ops)
  __syncthreads();

  // -------- epilogue: per-wave LDS repack -> coalesced 16B stores --------
  float bvj[4];
#pragma unroll
  for (int j = 0; j < 4; ++j)
    bvj[j] = bias ? bias[n0 + wn * 64 + j * 16 + l15] : 0.0f;

  if (flagOut && (*flag)) {
    // fp32 output: per m-frag 16 rows x 64 cols (stride 68 f32)
    float* scrf = (float*)smem + wave * 1088;
    float* Cf = (float*)C;
#pragma unroll
    for (int i = 0; i < 7; ++i) {
#pragma unroll
      for (int j = 0; j < 4; ++j)
#pragma unroll
        for (int rr = 0; rr < 4; ++rr)
          scrf[(quad * 4 + rr) * 68 + j * 16 + l15] = acc[i][j][rr] + bvj[j];
#pragma unroll
      for (int u = lane; u < 256; u += 64) {
        const int row = u >> 4, gr = u & 15;
        float4 vv = *(const float4*)(scrf + row * 68 + gr * 4);
        *(float4*)(Cf + (m0 + wm * 112 + i * 16 + row) * (size_t)N + n0 + wn * 64 + gr * 4) = vv;
      }
    }
  } else {
    // bf16 output: per m-frag 16 rows x 64 cols (stride 72 u16)
    u16* scr = smem + wave * 1152;
    u16* Cb = (u16*)C;
#pragma unroll
    for (int i = 0; i < 7; ++i) {
#pragma unroll
      for (int j = 0; j < 4; ++j)
#pragma unroll
        for (int rr = 0; rr < 4; ++rr)
          scr[(quad * 4 + rr) * 72 + j * 16 + l15] = f2bf(acc[i][j][rr] + bvj[j]);
#pragma unroll
      for (int u = lane; u < 128; u += 64) {
        const int row = u >> 3, gr = u & 7;
        int4 vv = *(const int4*)(scr + row * 72 + gr * 8);
        *(int4*)(Cb + (m0 + wm * 112 + i * 16 + row) * (size_t)N + n0 + wn * 64 + gr * 8) = vv;
      }
    }
  }
}

// ---------------- windowed attention ----------------
// one block (4 waves) per (b, l, head). K staged in LDS (XOR-64), V^T and P at
// stride 208 (2-way banks = free). LDS total 79.2 KB -> 2 blocks/CU.
__global__ __launch_bounds__(256, 2) void attn_win(
    const u16* __restrict__ qkv, u16* __restrict__ o)
{
  __shared__ u16 Ks[196 * 64];      // slot16B = row*8 + (g ^ (row&7))
  __shared__ u16 Vt[64 * 208];      // Vt[d][n], cols >=196 zero
  __shared__ u16 Pb[4][16 * 208];   // per-wave strip
  __shared__ int gtok[208];

  const int bid = blockIdx.x;
  const int h = bid % 12;
  const int l = (bid / 12) % 16;
  const int b = bid / 192;
  const int wr0 = (l >> 2) * 14, wc0 = (l & 3) * 14;
  const int baseTok = b * 3136;

  const int t = threadIdx.x, wave = t >> 6, lane = t & 63;
  const int quad = lane >> 4, l15 = lane & 15;

  if (t < 208) {
    const int nn = t < 196 ? t : 195;
    gtok[t] = baseTok + (wr0 + nn / 14) * 56 + wc0 + nn % 14;
  }
  __syncthreads();

  // stage K (rows 0..195, 8 d-groups, XOR layout)
  for (int u = t; u < 196 * 8; u += 256) {
    const int row = u >> 3, gg = u & 7;
    int4 kv = *(const int4*)(qkv + (size_t)gtok[row] * 2304 + 768 + h * 64 + gg * 8);
    *(int4*)(Ks + (row * 8 + (gg ^ (row & 7))) * 8) = kv;
  }
  // stage V transposed: Vt[d][n]
  for (int u = t; u < 208 * 8; u += 256) {
    const int n = u >> 3, dg = u & 7;
    int4 vv = {0, 0, 0, 0};
    if (n < 196)
      vv = *(const int4*)(qkv + (size_t)gtok[n] * 2304 + 1536 + h * 64 + dg * 8);
    const u16* pv = (const u16*)&vv;
#pragma unroll
    for (int j = 0; j < 8; ++j) Vt[(dg * 8 + j) * 208 + n] = pv[j];
  }
  __syncthreads();

  u16* Pw = &Pb[wave][0];
  const bf16x8 zerov = {};

  for (int rt = wave; rt < 13; rt += 4) {
    const int n0r = rt * 16;
    int qn = n0r + l15; if (qn > 195) qn = 195;
    const u16* qrow = qkv + (size_t)gtok[qn] * 2304 + h * 64;
    const bf16x8 aq0 = *(const bf16x8*)(qrow + quad * 8);
    const bf16x8 aq1 = *(const bf16x8*)(qrow + 32 + quad * 8);

    floatx4 s[13];
#pragma unroll
    for (int ct = 0; ct < 13; ++ct) {
      int kr = ct * 16 + l15; if (kr > 195) kr = 195;
      const bf16x8 bk0 = *(const bf16x8*)(Ks + (kr * 8 + (quad ^ (kr & 7))) * 8);
      const bf16x8 bk1 = *(const bf16x8*)(Ks + (kr * 8 + ((quad + 4) ^ (kr & 7))) * 8);
      floatx4 z = {};
      z = __builtin_amdgcn_mfma_f32_16x16x32_bf16(aq0, bk0, z, 0, 0, 0);
      z = __builtin_amdgcn_mfma_f32_16x16x32_bf16(aq1, bk1, z, 0, 0, 0);
      s[ct] = z;
    }

    // softmax: col = ct*16+l15, rows = n0r + quad*4 + r
    float mx[4], sm[4];
#pragma unroll
    for (int r = 0; r < 4; ++r) mx[r] = -3e38f;
#pragma unroll
    for (int ct = 0; ct < 13; ++ct) {
      const bool maskct = (ct == 12) && (l15 >= 4);
#pragma unroll
      for (int r = 0; r < 4; ++r) {
        float v = s[ct][r] * 0.125f;
        if (maskct) v = -3e38f;
        s[ct][r] = v;
        mx[r] = fmaxf(mx[r], v);
      }
    }
#pragma unroll
    for (int r = 0; r < 4; ++r)
      for (int off = 1; off < 16; off <<= 1)
        mx[r] = fmaxf(mx[r], __shfl_xor(mx[r], off, 64));
#pragma unroll
    for (int r = 0; r < 4; ++r) sm[r] = 0.0f;
#pragma unroll
    for (int ct = 0; ct < 13; ++ct)
#pragma unroll
      for (int r = 0; r < 4; ++r) {
        const float p = __expf(s[ct][r] - mx[r]);
        s[ct][r] = p;
        sm[r] += p;
      }
#pragma unroll
    for (int r = 0; r < 4; ++r)
      for (int off = 1; off < 16; off <<= 1)
        sm[r] += __shfl_xor(sm[r], off, 64);

    // P -> LDS (A-layout round trip); cols 0..207 fully covered
#pragma unroll
    for (int ct = 0; ct < 13; ++ct)
#pragma unroll
      for (int r = 0; r < 4; ++r)
        Pw[(quad * 4 + r) * 208 + ct * 16 + l15] = f2bf(s[ct][r]);

    // O = P @ V: 6 full K=32 steps + masked tail (k 192..207 real)
    floatx4 oacc[4] = {};
#pragma unroll
    for (int ks = 0; ks < 6; ++ks) {
      const bf16x8 ap = *(const bf16x8*)(Pw + l15 * 208 + ks * 32 + quad * 8);
#pragma unroll
      for (int nt = 0; nt < 4; ++nt) {
        const bf16x8 bv = *(const bf16x8*)(Vt + (nt * 16 + l15) * 208 + ks * 32 + quad * 8);
        oacc[nt] = __builtin_amdgcn_mfma_f32_16x16x32_bf16(ap, bv, oacc[nt], 0, 0, 0);
      }
    }
    {
      const int off = 192 + (quad & 1) * 8;
      bf16x8 ap = *(const bf16x8*)(Pw + l15 * 208 + off);
      if (quad >= 2) ap = zerov;
#pragma unroll
      for (int nt = 0; nt < 4; ++nt) {
        const bf16x8 bv = *(const bf16x8*)(Vt + (nt * 16 + l15) * 208 + off);
        oacc[nt] = __builtin_amdgcn_mfma_f32_16x16x32_bf16(ap, bv, oacc[nt], 0, 0, 0);
      }
    }

    float rs[4];
#pragma unroll
    for (int r = 0; r < 4; ++r) rs[r] = 1.0f / sm[r];

    // O -> Pw repack -> coalesced 16B stores
#pragma unroll
    for (int nt = 0; nt < 4; ++nt)
#pragma unroll
      for (int r = 0; r < 4; ++r)
        Pw[(quad * 4 + r) * 208 + nt * 16 + l15] = f2bf(oacc[nt][r] * rs[r]);
#pragma unroll
    for (int u = lane; u < 128; u += 64) {
      const int row = u >> 3, gr = u & 7;
      const int n = n0r + row;
      if (n < 196) {
        int4 vv = *(const int4*)(Pw + row * 208 + gr * 8);
        *(int4*)(o + (size_t)gtok[n] * 768 + h * 64 + gr * 8) = vv;
      }
    }
  }
}

extern "C" void kernel_launch(void* const* d_in, const int* in_sizes, int n_in,
                              void* d_out, int out_size, void* d_ws, size_t ws_size,
                              hipStream_t stream)
{
  const void* x     = d_in[0];  // [8,3136,768]   fp32 or bf16
  const void* wqkv  = d_in[1];  // [768,2304]
  const void* wproj = d_in[2];  // [768,768]
  const void* bproj = d_in[3];  // [768]

  char* ws = (char*)d_ws;
  int*   flag   = (int*)ws;                         // 16 B
  float* bprojF = (float*)(ws + 16);                // 768 f32
  u16*   wqkvT  = (u16*)(ws + 4096);                // 2304*768 bf16
  u16*   wprojT = (u16*)(ws + 3543040);             // 768*768  bf16
  u16*   qkvbuf = (u16*)(ws + 4722688);             // 25088*2304 bf16
  u16*   xb     = (u16*)(ws + 120328192);           // 25088*768 bf16 (reused as attn out)
  u16*   attno  = xb;

  detect_k<<<1, 256, 0, stream>>>((const u16*)wqkv, flag);
  cast_x_k<<<dim3(18816), 256, 0, stream>>>(x, xb, 4816896, flag);
  ct_transpose_k<<<dim3(72, 24), 256, 0, stream>>>(wqkv, wqkvT, 768, 2304, flag);
  ct_transpose_k<<<dim3(24, 24), 256, 0, stream>>>(wproj, wprojT, 768, 768, flag);
  bias_cast_k<<<dim3(3), 256, 0, stream>>>(bproj, bprojF, 768, flag);

  // QKV: M=25088 (112 tiles of 224), N=2304 (9 tiles) -> 1008 blocks (3.94 rounds)
  gemm256<<<dim3(1008), 512, 0, stream>>>(xb, wqkvT, (const float*)nullptr, qkvbuf,
                                          25088, 2304, 768, flag, 0);
  attn_win<<<dim3(1536), 256, 0, stream>>>(qkvbuf, attno);
  // proj: M=25088 (112 tiles), N=768 (3 tiles) -> 336 blocks
  gemm256<<<dim3(336), 512, 0, stream>>>(attno, wprojT, bprojF, d_out,
                                         25088, 768, 768, flag, 1);
}